// Round 3
// baseline (98.965 us; speedup 1.0000x reference)
//
#include <hip/hip_runtime.h>

// LateralEI: out = GAIN * rownorm(K) @ h, K = 0.8*exp(-d2/0.72) - exp(-d2/2.88)
// z: [8192][2] f32, h: [8192][128] f32, out: [8192][128] f32
//
// R9: traffic cut. R8 (halved per-CU LDS b128, halved B-fetch, 2x rows/wave,
// halved occupancy) == R7 == R6 == R4 within noise => main is NOT LDS-,
// occupancy-, MFMA-, or B-fetch-bound. Only counter-backed lever left:
// controllable HBM bytes. At NKS=16 the partb partial round-trip is
// 32 MiB write + 32 MiB read (~10 us at 6.4 TB/s). R9 = exact R7 structure
// (4 waves x 32 rows, grid 512 = 2 blocks/CU, depth-2 ring, vmcnt(2)+bar,
// bar2 WAR) with NKS=8: KSL=1024, NITER=32, NRT=64. Per-CU iteration count,
// wave count, LDS b128 count, B-fetch demand all IDENTICAL to R7; only the
// partial traffic halves (-16 MiB main WRITE, -16 MiB reduce FETCH).
// Predict 94.5 -> ~89 us. If flat: total is pinned by the harness's 256 MiB
// ws poison fill (41 us, 82% HBM peak, visible in top-5) + fixed overhead,
// i.e. the kernel pipeline is at its practical floor.

typedef float f32x4 __attribute__((ext_vector_type(4)));
typedef float f32x2 __attribute__((ext_vector_type(2)));
typedef short s16x8 __attribute__((ext_vector_type(8)));
typedef unsigned int u32x4 __attribute__((ext_vector_type(4)));

#define NPTS 8192
#define DH 128
#define A_I (-0.5009357781f)  // -log2(e)/(2*1.2^2); A_E = 4*A_I
#define GAIN_C 0.05f

#define NKS 8       // cross-block K-slices (1024 k each)
#define KSL 1024    // k per slice
#define NITER 32    // 1024 / 32
#define NRT 64      // row-tiles (128 rows each: 4 waves x 32 rows)

// ---------- pre-pass: h [8192][128] f32 -> hTf fragment-major bf16 (R4-verified) ----------
__global__ __launch_bounds__(256) void h_to_hTf(
    const float* __restrict__ h, unsigned short* __restrict__ hTf) {
  __shared__ unsigned int tileW[DH * 17];  // [n][kp], kp = k-pair 0..15
  const int t = threadIdx.x;
  const int k5 = blockIdx.x;
  const int n = t & 127;
  const int g = t >> 7;  // 0..1
#pragma unroll
  for (int p = 0; p < 8; ++p) {
    const int kp = g * 8 + p;
    unsigned int a = __float_as_uint(h[(k5 * 32 + 2 * kp) * DH + n]);
    unsigned int b = __float_as_uint(h[(k5 * 32 + 2 * kp + 1) * DH + n]);
    a = (a + 0x7fffu + ((a >> 16) & 1u)) >> 16;          // RNE low half
    b = (b + 0x7fffu + ((b >> 16) & 1u)) & 0xffff0000u;  // RNE high half
    tileW[n * 17 + kp] = a | b;
  }
  __syncthreads();
#pragma unroll
  for (int it = 0; it < 2; ++it) {
    const int u = t + it * 256;
    const int cf = u >> 6;
    const int lane = u & 63;
    const int nf = lane & 15;
    const int q = lane >> 4;
    const int n2 = cf * 16 + nf;
    u32x4 val;
#pragma unroll
    for (int i = 0; i < 4; ++i) val[i] = tileW[n2 * 17 + q * 4 + i];
    *(u32x4*)(hTf + k5 * 4096 + u * 8) = val;
  }
}

// stage one 8KB B-tile into a ring slot: 256 threads x 2 x 16B (2 instrs/wave)
__device__ __forceinline__ void produce_tile(const char* src, char* dst, int t) {
  __builtin_amdgcn_global_load_lds(
      (const __attribute__((address_space(1))) unsigned int*)(src + t * 16),
      (__attribute__((address_space(3))) unsigned int*)(dst + t * 16), 16, 0, 0);
  __builtin_amdgcn_global_load_lds(
      (const __attribute__((address_space(1))) unsigned int*)(src + 4096 + t * 16),
      (__attribute__((address_space(3))) unsigned int*)(dst + 4096 + t * 16), 16, 0, 0);
}

// ---------- main fused kernel ----------
__global__ __launch_bounds__(256, 4) void lateral_ei_main(
    const float* __restrict__ z, const unsigned short* __restrict__ hTf,
    unsigned short* __restrict__ partb, float* __restrict__ prs) {
  __shared__ __align__(16) unsigned short ring[2][4096];  // 2 x 8KB
  __shared__ __align__(16) float zxy[KSL * 2];            // 8KB (x,y) per k
  __shared__ __align__(16) float zaz[KSL];                // 4KB A_I*|z_k|^2

  const int t = threadIdx.x;
  const int lane = t & 63;
  const int w = t >> 6;  // wave 0..3
  const int rt = blockIdx.x & (NRT - 1);
  const int ks = blockIdx.x >> 6;  // 0..NKS-1
  const int i0 = rt * 128 + w * 32;
  const int nf = lane & 15;
  const int q = lane >> 4;
  const int k0 = ks * KSL;

  // zi constants for rows i0+nf, i0+16+nf
  const float zx0 = z[(i0 + nf) * 2], zy0 = z[(i0 + nf) * 2 + 1];
  const float zx1 = z[(i0 + 16 + nf) * 2], zy1 = z[(i0 + 16 + nf) * 2 + 1];
  const float cA0 = A_I * (zx0 * zx0 + zy0 * zy0);
  const float cA1 = A_I * (zx1 * zx1 + zy1 * zy1);
  const float cX0 = -2.f * A_I * zx0, cY0 = -2.f * A_I * zy0;
  const float cX1 = -2.f * A_I * zx1, cY1 = -2.f * A_I * zy1;

  const char* srcB = (const char*)hTf + (size_t)ks * (NITER * 8192);
  char* ringB = (char*)&ring[0][0];

  // ---- preamble: stage slot 0; stage z/az slice (4 k per thread) ----
  produce_tile(srcB, ringB, t);
  {
    const int k4 = t * 4;
    const f32x4 p0 = *(const f32x4*)(z + (size_t)(k0 + k4) * 2);      // x,y of k4,k4+1
    const f32x4 p1 = *(const f32x4*)(z + (size_t)(k0 + k4 + 2) * 2);  // x,y of k4+2,k4+3
    *(f32x4*)(zxy + k4 * 2) = p0;
    *(f32x4*)(zxy + k4 * 2 + 4) = p1;
    f32x4 az;
    az[0] = A_I * fmaf(p0[1], p0[1], p0[0] * p0[0]);
    az[1] = A_I * fmaf(p0[3], p0[3], p0[2] * p0[2]);
    az[2] = A_I * fmaf(p1[1], p1[1], p1[0] * p1[0]);
    az[3] = A_I * fmaf(p1[3], p1[3], p1[2] * p1[2]);
    *(f32x4*)(zaz + k4) = az;
  }
  __syncthreads();  // drains preamble vmem (incl. produce(0)) + LDS writes

  f32x4 acc0[8], acc1[8];
#pragma unroll
  for (int cf = 0; cf < 8; ++cf) {
    acc0[cf] = (f32x4){0.f, 0.f, 0.f, 0.f};
    acc1[cf] = (f32x4){0.f, 0.f, 0.f, 0.f};
  }
  float rs0a = 0.f, rs0b = 0.f, rs1a = 0.f, rs1b = 0.f;

#pragma unroll 1
  for (int it = 0; it < NITER; ++it) {
    const int nit = (it + 1) & (NITER - 1);  // wrap: re-stages tile 0, never read

    // stage iter it+1 — the loop's ONLY vmem ops (2 instrs/wave)
    produce_tile(srcB + nit * 8192, ringB + ((it + 1) & 1) * 8192, t);

    // ---- w-production for iter it (z/az from LDS, quad-uniform broadcast)
    const float* zp_ = zxy + it * 64 + q * 16;
    const f32x4 zcA = *(const f32x4*)(zp_ + 0);
    const f32x4 zcB = *(const f32x4*)(zp_ + 4);
    const f32x4 zcC = *(const f32x4*)(zp_ + 8);
    const f32x4 zcD = *(const f32x4*)(zp_ + 12);
    const f32x4 az0 = *(const f32x4*)(zaz + it * 32 + q * 8);
    const f32x4 az1 = *(const f32x4*)(zaz + it * 32 + q * 8 + 4);

    float wv0[8], wv1[8];
#pragma unroll
    for (int j = 0; j < 8; ++j) {
      const f32x4 zp = (j < 2) ? zcA : (j < 4) ? zcB : (j < 6) ? zcC : zcD;
      const float xj = zp[(j & 1) * 2], yj = zp[(j & 1) * 2 + 1];
      const float az = (j < 4) ? az0[j] : az1[j - 4];
      const float u0 = fmaf(cX0, xj, fmaf(cY0, yj, cA0 + az));
      const float u1 = fmaf(cX1, xj, fmaf(cY1, yj, cA1 + az));
      const float ei0 = __builtin_amdgcn_exp2f(u0);
      const float ei1 = __builtin_amdgcn_exp2f(u1);
      const float s0 = ei0 * ei0, s1 = ei1 * ei1;
      const float w0 = fmaf(0.8f, s0 * s0, -ei0);  // e_E = e_I^4
      const float w1 = fmaf(0.8f, s1 * s1, -ei1);
      wv0[j] = w0; wv1[j] = w1;
      if (j & 1) { rs0b += w0; rs1b += w1; } else { rs0a += w0; rs1a += w1; }
    }
    union { unsigned int u[4]; s16x8 v; } af0, af1;
#pragma unroll
    for (int p = 0; p < 4; ++p) {
      af0.u[p] = __builtin_amdgcn_perm(__float_as_uint(wv0[2 * p + 1]),
                                       __float_as_uint(wv0[2 * p]), 0x07060302);
      af1.u[p] = __builtin_amdgcn_perm(__float_as_uint(wv1[2 * p + 1]),
                                       __float_as_uint(wv1[2 * p]), 0x07060302);
    }
    const s16x8 a0 = af0.v, a1 = af1.v;

    // own produce(it) drained (only produce(it+1)'s 2 remain) -> bar1:
    // slot it fully landed for all 4 waves. Prefetch stays in flight.
    asm volatile("s_waitcnt vmcnt(2)\n\ts_barrier" ::: "memory");

    // ---- consume slot it: 8 B-frags via ds_read_b128, 16 MFMAs
    const char* rbl = ringB + (it & 1) * 8192 + lane * 16;
#pragma unroll
    for (int cf = 0; cf < 8; ++cf) {
      const s16x8 bfr = *(const s16x8*)(rbl + cf * 1024);
      acc0[cf] = __builtin_amdgcn_mfma_f32_16x16x32_bf16(a0, bfr, acc0[cf], 0, 0, 0);
      acc1[cf] = __builtin_amdgcn_mfma_f32_16x16x32_bf16(a1, bfr, acc1[cf], 0, 0, 0);
    }
    // bar2: depth-2 WAR — all waves' reads of slot (it&1) done before any
    // produce(it+2) (next body top) can touch it.
    asm volatile("s_barrier" ::: "memory");
  }

  // ---- rowsum: sum 4 quad-partials per row (lanes nf,nf+16,nf+32,nf+48)
  float rs0 = rs0a + rs0b, rs1 = rs1a + rs1b;
  rs0 += __shfl_xor(rs0, 16);
  rs0 += __shfl_xor(rs0, 32);
  rs1 += __shfl_xor(rs1, 16);
  rs1 += __shfl_xor(rs1, 32);
  if (lane < 16) {
    prs[ks * NPTS + i0 + nf] = rs0;
    prs[ks * NPTS + i0 + 16 + nf] = rs1;
  }

  // ---- partial store, bf16 RNE (C/D layout: col=cf*16+nf, row=q*4+r)
  unsigned short* pb = partb + (size_t)ks * (NPTS * DH);
#pragma unroll
  for (int cf = 0; cf < 8; ++cf)
#pragma unroll
    for (int r = 0; r < 4; ++r) {
      unsigned int u0 = __float_as_uint(acc0[cf][r]);
      unsigned int u1 = __float_as_uint(acc1[cf][r]);
      u0 = (u0 + 0x7fffu + ((u0 >> 16) & 1u)) >> 16;
      u1 = (u1 + 0x7fffu + ((u1 >> 16) & 1u)) >> 16;
      pb[(i0 + q * 4 + r) * DH + cf * 16 + nf] = (unsigned short)u0;
      pb[(i0 + 16 + q * 4 + r) * DH + cf * 16 + nf] = (unsigned short)u1;
    }
}

// ---------- reduce NKS K-slice partials + normalize + scale ----------
__global__ __launch_bounds__(256) void reduce_scale(
    const unsigned short* __restrict__ partb, const float* __restrict__ prs,
    float* __restrict__ out) {
  const int gid = blockIdx.x * 256 + threadIdx.x;  // 8 cols each
  const int base = gid * 8;
  const int row = gid >> 4;
  float c[8] = {0.f, 0.f, 0.f, 0.f, 0.f, 0.f, 0.f, 0.f};
  float rsum = 0.f;
#pragma unroll
  for (int s = 0; s < NKS; ++s) {
    const u32x4 v = *(const u32x4*)(partb + (size_t)s * (NPTS * DH) + base);
#pragma unroll
    for (int i = 0; i < 4; ++i) {
      c[2 * i] += __uint_as_float(v[i] << 16);
      c[2 * i + 1] += __uint_as_float(v[i] & 0xffff0000u);
    }
    rsum += prs[s * NPTS + row];
  }
  const float scl = GAIN_C / (rsum + 1e-6f);
  f32x4 o0 = {c[0] * scl, c[1] * scl, c[2] * scl, c[3] * scl};
  f32x4 o1 = {c[4] * scl, c[5] * scl, c[6] * scl, c[7] * scl};
  *(f32x4*)(out + base) = o0;
  *(f32x4*)(out + base + 4) = o1;
}

extern "C" void kernel_launch(void* const* d_in, const int* in_sizes, int n_in,
                              void* d_out, int out_size, void* d_ws, size_t ws_size,
                              hipStream_t stream) {
  (void)in_sizes; (void)n_in; (void)out_size; (void)ws_size;
  const float* z = (const float*)d_in[0];
  const float* h = (const float*)d_in[1];
  float* out = (float*)d_out;
  unsigned short* hTf = (unsigned short*)d_ws;                          // 2 MiB
  unsigned short* partb = (unsigned short*)((char*)d_ws + (2u << 20));  // 16 MiB bf16
  float* prs = (float*)((char*)d_ws + (18u << 20));                     // 256 KiB

  h_to_hTf<<<NPTS / 32, 256, 0, stream>>>(h, hTf);
  lateral_ei_main<<<NRT * NKS, 256, 0, stream>>>(z, hTf, partb, prs);
  reduce_scale<<<(NPTS * DH / 8) / 256, 256, 0, stream>>>(partb, prs, out);
}

// Round 4
// 94.120 us; speedup vs baseline: 1.0515x; 1.0515x over previous
//
#include <hip/hip_runtime.h>

// LateralEI: out = GAIN * rownorm(K) @ h, K = 0.8*exp(-d2/0.72) - exp(-d2/2.88)
// z: [8192][2] f32, h: [8192][128] f32, out: [8192][128] f32
//
// R10 = revert to R7 (round-0 verbatim, best-measured structure, 94.05 us).
// Session findings: timed dur = ~82 us fixed harness poison-fill cost (the
// only >=40 us dispatches, 268 MB WRITE @ 82% HBM peak, 2 fill-equivalents)
// + ~12 us controllable kernels (h_to_hTf ~1, main ~7 = VALU floor of
// 8192^2 x ~6 ops/elem, reduce ~4). R4/R6/R7/R8 plateau 93.6-94.5 = sub-us
// differences in the 12 us region. R9 (NITER=32 @ 2 blk/CU) regressed 4.5 us:
// doubled barrier-chain length at halved block concurrency adds pacing
// stalls on top of the VALU floor. R7's geometry (16-iter chains, 4 blk/CU,
// 4 waves/SIMD) is the plateau's sweet spot.

typedef float f32x4 __attribute__((ext_vector_type(4)));
typedef float f32x2 __attribute__((ext_vector_type(2)));
typedef short s16x8 __attribute__((ext_vector_type(8)));
typedef unsigned int u32x4 __attribute__((ext_vector_type(4)));

#define NPTS 8192
#define DH 128
#define A_I (-0.5009357781f)  // -log2(e)/(2*1.2^2); A_E = 4*A_I
#define GAIN_C 0.05f

#define NKS 16      // cross-block K-slices (512 k each)
#define KSL 512     // k per slice
#define NITER 16    // 512 / 32
#define NRT 64      // row-tiles (128 rows each)

// ---------- pre-pass: h [8192][128] f32 -> hTf fragment-major bf16 (R4-verified) ----------
__global__ __launch_bounds__(256) void h_to_hTf(
    const float* __restrict__ h, unsigned short* __restrict__ hTf) {
  __shared__ unsigned int tileW[DH * 17];  // [n][kp], kp = k-pair 0..15
  const int t = threadIdx.x;
  const int k5 = blockIdx.x;
  const int n = t & 127;
  const int g = t >> 7;  // 0..1
#pragma unroll
  for (int p = 0; p < 8; ++p) {
    const int kp = g * 8 + p;
    unsigned int a = __float_as_uint(h[(k5 * 32 + 2 * kp) * DH + n]);
    unsigned int b = __float_as_uint(h[(k5 * 32 + 2 * kp + 1) * DH + n]);
    a = (a + 0x7fffu + ((a >> 16) & 1u)) >> 16;          // RNE low half
    b = (b + 0x7fffu + ((b >> 16) & 1u)) & 0xffff0000u;  // RNE high half
    tileW[n * 17 + kp] = a | b;
  }
  __syncthreads();
#pragma unroll
  for (int it = 0; it < 2; ++it) {
    const int u = t + it * 256;
    const int cf = u >> 6;
    const int lane = u & 63;
    const int nf = lane & 15;
    const int q = lane >> 4;
    const int n2 = cf * 16 + nf;
    u32x4 val;
#pragma unroll
    for (int i = 0; i < 4; ++i) val[i] = tileW[n2 * 17 + q * 4 + i];
    *(u32x4*)(hTf + k5 * 4096 + u * 8) = val;
  }
}

// stage one 8KB B-tile into a ring slot: 256 threads x 2 x 16B (2 instrs/wave)
__device__ __forceinline__ void produce_tile(const char* src, char* dst, int t) {
  __builtin_amdgcn_global_load_lds(
      (const __attribute__((address_space(1))) unsigned int*)(src + t * 16),
      (__attribute__((address_space(3))) unsigned int*)(dst + t * 16), 16, 0, 0);
  __builtin_amdgcn_global_load_lds(
      (const __attribute__((address_space(1))) unsigned int*)(src + 4096 + t * 16),
      (__attribute__((address_space(3))) unsigned int*)(dst + 4096 + t * 16), 16, 0, 0);
}

// ---------- main fused kernel ----------
__global__ __launch_bounds__(256, 4) void lateral_ei_main(
    const float* __restrict__ z, const unsigned short* __restrict__ hTf,
    unsigned short* __restrict__ partb, float* __restrict__ prs) {
  __shared__ __align__(16) unsigned short ring[2][4096];  // 2 x 8KB
  __shared__ __align__(16) float zxy[KSL * 2];            // 4KB (x,y) per k
  __shared__ __align__(16) float zaz[KSL];                // 2KB A_I*|z_k|^2

  const int t = threadIdx.x;
  const int lane = t & 63;
  const int w = t >> 6;  // wave 0..3
  const int rt = blockIdx.x & (NRT - 1);
  const int ks = blockIdx.x >> 6;  // 0..NKS-1
  const int i0 = rt * 128 + w * 32;
  const int nf = lane & 15;
  const int q = lane >> 4;
  const int k0 = ks * KSL;

  // zi constants for rows i0+nf, i0+16+nf
  const float zx0 = z[(i0 + nf) * 2], zy0 = z[(i0 + nf) * 2 + 1];
  const float zx1 = z[(i0 + 16 + nf) * 2], zy1 = z[(i0 + 16 + nf) * 2 + 1];
  const float cA0 = A_I * (zx0 * zx0 + zy0 * zy0);
  const float cA1 = A_I * (zx1 * zx1 + zy1 * zy1);
  const float cX0 = -2.f * A_I * zx0, cY0 = -2.f * A_I * zy0;
  const float cX1 = -2.f * A_I * zx1, cY1 = -2.f * A_I * zy1;

  const char* srcB = (const char*)hTf + (size_t)ks * (16 * 8192);
  char* ringB = (char*)&ring[0][0];

  // ---- preamble: stage slot 0; stage z/az slice (2 k per thread) ----
  produce_tile(srcB, ringB, t);
  {
    const int k2 = t * 2;
    const f32x4 p = *(const f32x4*)(z + (size_t)(k0 + k2) * 2);  // x0,y0,x1,y1
    *(f32x4*)(zxy + k2 * 2) = p;
    f32x2 az;
    az[0] = A_I * fmaf(p[1], p[1], p[0] * p[0]);
    az[1] = A_I * fmaf(p[3], p[3], p[2] * p[2]);
    *(f32x2*)(zaz + k2) = az;
  }
  __syncthreads();  // drains preamble vmem (incl. produce(0)) + LDS writes

  f32x4 acc0[8], acc1[8];
#pragma unroll
  for (int cf = 0; cf < 8; ++cf) {
    acc0[cf] = (f32x4){0.f, 0.f, 0.f, 0.f};
    acc1[cf] = (f32x4){0.f, 0.f, 0.f, 0.f};
  }
  float rs0a = 0.f, rs0b = 0.f, rs1a = 0.f, rs1b = 0.f;

#pragma unroll 1
  for (int it = 0; it < NITER; ++it) {
    const int nit = (it + 1) & (NITER - 1);  // wrap: re-stages tile 0, never read

    // stage iter it+1 — the loop's ONLY vmem ops (2 instrs/wave)
    produce_tile(srcB + nit * 8192, ringB + ((it + 1) & 1) * 8192, t);

    // ---- w-production for iter it (z/az from LDS, quad-uniform broadcast)
    const float* zp_ = zxy + it * 64 + q * 16;
    const f32x4 zcA = *(const f32x4*)(zp_ + 0);
    const f32x4 zcB = *(const f32x4*)(zp_ + 4);
    const f32x4 zcC = *(const f32x4*)(zp_ + 8);
    const f32x4 zcD = *(const f32x4*)(zp_ + 12);
    const f32x4 az0 = *(const f32x4*)(zaz + it * 32 + q * 8);
    const f32x4 az1 = *(const f32x4*)(zaz + it * 32 + q * 8 + 4);

    float wv0[8], wv1[8];
#pragma unroll
    for (int j = 0; j < 8; ++j) {
      const f32x4 zp = (j < 2) ? zcA : (j < 4) ? zcB : (j < 6) ? zcC : zcD;
      const float xj = zp[(j & 1) * 2], yj = zp[(j & 1) * 2 + 1];
      const float az = (j < 4) ? az0[j] : az1[j - 4];
      const float u0 = fmaf(cX0, xj, fmaf(cY0, yj, cA0 + az));
      const float u1 = fmaf(cX1, xj, fmaf(cY1, yj, cA1 + az));
      const float ei0 = __builtin_amdgcn_exp2f(u0);
      const float ei1 = __builtin_amdgcn_exp2f(u1);
      const float s0 = ei0 * ei0, s1 = ei1 * ei1;
      const float w0 = fmaf(0.8f, s0 * s0, -ei0);  // e_E = e_I^4
      const float w1 = fmaf(0.8f, s1 * s1, -ei1);
      wv0[j] = w0; wv1[j] = w1;
      if (j & 1) { rs0b += w0; rs1b += w1; } else { rs0a += w0; rs1a += w1; }
    }
    union { unsigned int u[4]; s16x8 v; } af0, af1;
#pragma unroll
    for (int p = 0; p < 4; ++p) {
      af0.u[p] = __builtin_amdgcn_perm(__float_as_uint(wv0[2 * p + 1]),
                                       __float_as_uint(wv0[2 * p]), 0x07060302);
      af1.u[p] = __builtin_amdgcn_perm(__float_as_uint(wv1[2 * p + 1]),
                                       __float_as_uint(wv1[2 * p]), 0x07060302);
    }
    const s16x8 a0 = af0.v, a1 = af1.v;

    // own produce(it) drained (only produce(it+1)'s 2 remain) -> bar1:
    // slot it fully landed for all 4 waves. Prefetch stays in flight.
    asm volatile("s_waitcnt vmcnt(2)\n\ts_barrier" ::: "memory");

    // ---- consume slot it: 8 B-frags via ds_read_b128, 16 MFMAs
    const char* rbl = ringB + (it & 1) * 8192 + lane * 16;
#pragma unroll
    for (int cf = 0; cf < 8; ++cf) {
      const s16x8 bfr = *(const s16x8*)(rbl + cf * 1024);
      acc0[cf] = __builtin_amdgcn_mfma_f32_16x16x32_bf16(a0, bfr, acc0[cf], 0, 0, 0);
      acc1[cf] = __builtin_amdgcn_mfma_f32_16x16x32_bf16(a1, bfr, acc1[cf], 0, 0, 0);
    }
    // bar2: depth-2 WAR — all waves' reads of slot (it&1) done before any
    // produce(it+2) (next body top) can touch it.
    asm volatile("s_barrier" ::: "memory");
  }

  // ---- rowsum: sum 4 quad-partials per row (lanes nf,nf+16,nf+32,nf+48)
  float rs0 = rs0a + rs0b, rs1 = rs1a + rs1b;
  rs0 += __shfl_xor(rs0, 16);
  rs0 += __shfl_xor(rs0, 32);
  rs1 += __shfl_xor(rs1, 16);
  rs1 += __shfl_xor(rs1, 32);
  if (lane < 16) {
    prs[ks * NPTS + i0 + nf] = rs0;
    prs[ks * NPTS + i0 + 16 + nf] = rs1;
  }

  // ---- partial store, bf16 RNE (C/D layout: col=cf*16+nf, row=q*4+r)
  unsigned short* pb = partb + (size_t)ks * (NPTS * DH);
#pragma unroll
  for (int cf = 0; cf < 8; ++cf)
#pragma unroll
    for (int r = 0; r < 4; ++r) {
      unsigned int u0 = __float_as_uint(acc0[cf][r]);
      unsigned int u1 = __float_as_uint(acc1[cf][r]);
      u0 = (u0 + 0x7fffu + ((u0 >> 16) & 1u)) >> 16;
      u1 = (u1 + 0x7fffu + ((u1 >> 16) & 1u)) >> 16;
      pb[(i0 + q * 4 + r) * DH + cf * 16 + nf] = (unsigned short)u0;
      pb[(i0 + 16 + q * 4 + r) * DH + cf * 16 + nf] = (unsigned short)u1;
    }
}

// ---------- reduce NKS K-slice partials + normalize + scale ----------
__global__ __launch_bounds__(256) void reduce_scale(
    const unsigned short* __restrict__ partb, const float* __restrict__ prs,
    float* __restrict__ out) {
  const int gid = blockIdx.x * 256 + threadIdx.x;  // 8 cols each
  const int base = gid * 8;
  const int row = gid >> 4;
  float c[8] = {0.f, 0.f, 0.f, 0.f, 0.f, 0.f, 0.f, 0.f};
  float rsum = 0.f;
#pragma unroll
  for (int s = 0; s < NKS; ++s) {
    const u32x4 v = *(const u32x4*)(partb + (size_t)s * (NPTS * DH) + base);
#pragma unroll
    for (int i = 0; i < 4; ++i) {
      c[2 * i] += __uint_as_float(v[i] << 16);
      c[2 * i + 1] += __uint_as_float(v[i] & 0xffff0000u);
    }
    rsum += prs[s * NPTS + row];
  }
  const float scl = GAIN_C / (rsum + 1e-6f);
  f32x4 o0 = {c[0] * scl, c[1] * scl, c[2] * scl, c[3] * scl};
  f32x4 o1 = {c[4] * scl, c[5] * scl, c[6] * scl, c[7] * scl};
  *(f32x4*)(out + base) = o0;
  *(f32x4*)(out + base + 4) = o1;
}

extern "C" void kernel_launch(void* const* d_in, const int* in_sizes, int n_in,
                              void* d_out, int out_size, void* d_ws, size_t ws_size,
                              hipStream_t stream) {
  (void)in_sizes; (void)n_in; (void)out_size; (void)ws_size;
  const float* z = (const float*)d_in[0];
  const float* h = (const float*)d_in[1];
  float* out = (float*)d_out;
  unsigned short* hTf = (unsigned short*)d_ws;                          // 2 MiB
  unsigned short* partb = (unsigned short*)((char*)d_ws + (2u << 20));  // 32 MiB bf16
  float* prs = (float*)((char*)d_ws + (34u << 20));                     // 512 KiB

  h_to_hTf<<<NPTS / 32, 256, 0, stream>>>(h, hTf);
  lateral_ei_main<<<NRT * NKS, 256, 0, stream>>>(z, hTf, partb, prs);
  reduce_scale<<<(NPTS * DH / 8) / 256, 256, 0, stream>>>(partb, prs, out);
}